// Round 8
// baseline (668.797 us; speedup 1.0000x reference)
//
#include <hip/hip_runtime.h>
#include <stdint.h>

// FP32->FP64 bit-pulse converter, round 8.
// Round 7 structure (best: 657 us) + 2 tiles per wave with both loads
// issued before the first ballot (read MLP; tile 1's ballot waits only
// vmcnt(1)). Everything else identical: ballot pack, one convert/lane,
// ds_bpermute redistribution, contiguous 1024-B-span nontemporal stores.

typedef float fvec4 __attribute__((ext_vector_type(4)));

__device__ __forceinline__ uint32_t spread4(uint32_t x) {
    // spread low 8 bits: bit i -> bit 4*i
    x &= 0xffu;
    x = (x | (x << 12)) & 0x000F000Fu;
    x = (x | (x << 6))  & 0x03030303u;
    x = (x | (x << 3))  & 0x11111111u;
    return x;
}

__device__ __forceinline__ uint64_t shfl64(uint64_t x, int srcLane) {
    int addr = srcLane << 2;  // ds_bpermute index is lane*4 bytes
    uint32_t lo = (uint32_t)__builtin_amdgcn_ds_bpermute(addr, (int)(uint32_t)x);
    uint32_t hi = (uint32_t)__builtin_amdgcn_ds_bpermute(addr, (int)(uint32_t)(x >> 32));
    return ((uint64_t)hi << 32) | lo;
}

__device__ __forceinline__ fvec4 nib2f(uint32_t nib) {
    fvec4 f;
    f.x = (nib & 1u) ? 1.0f : 0.0f;
    f.y = (nib & 2u) ? 1.0f : 0.0f;
    f.z = (nib & 4u) ? 1.0f : 0.0f;
    f.w = (nib & 8u) ? 1.0f : 0.0f;
    return f;
}

__device__ __forceinline__ void process_tile(fvec4 g, int sh, int src0,
                                             int nsh, fvec4* __restrict__ ob) {
    // ---- pack all 256 tile bits: bit k of bc = (elem 4k+c of tile) != 0 ----
    uint64_t b0 = __ballot(g.x != 0.0f);
    uint64_t b1 = __ballot(g.y != 0.0f);
    uint64_t b2 = __ballot(g.z != 0.0f);
    uint64_t b3 = __ballot(g.w != 0.0f);

    // ---- rebuild this lane's row word (row = lane/8, MSB-first) ----
    uint32_t u = spread4((uint32_t)(b0 >> sh))
               | (spread4((uint32_t)(b1 >> sh)) << 1)
               | (spread4((uint32_t)(b2 >> sh)) << 2)
               | (spread4((uint32_t)(b3 >> sh)) << 3);

    // ---- FP32 -> FP64 bit conversion (once per lane) ----
    uint32_t v = __brev(u);              // standard IEEE FP32 word
    uint32_t E = (v >> 23) & 0xffu;
    uint32_t M = v & 0x7fffffu;
    uint64_t S = (uint64_t)(v >> 31);
    uint64_t E64 = E ? (uint64_t)(E + 896u) : 0ull;  // rebias 1023-127
    uint64_t M64 = (uint64_t)M << 29;
    if (E == 255u) {                     // Inf / NaN
        E64 = 2047ull;
        M64 = M ? (1ull << 51) : 0ull;   // quiet NaN: mantissa MSB only
    }
    uint64_t v64 = (S << 63) | (E64 << 52) | M64;
    uint64_t rr  = __brevll(v64);        // bit j == output element j of row

    // ---- redistribute rows so each store is a contiguous 1024-B span ----
    uint64_t r0 = shfl64(rr, src0);      // row lane/16      (chunks 0..63)
    uint64_t r1 = shfl64(rr, src0 + 32); // row 4 + lane/16  (chunks 64..127)

    fvec4 f0 = nib2f((uint32_t)(r0 >> nsh) & 0xfu);
    fvec4 f1 = nib2f((uint32_t)(r1 >> nsh) & 0xfu);

    __builtin_nontemporal_store(f0, ob);       // chunks 0..63
    __builtin_nontemporal_store(f1, ob + 64);  // chunks 64..127
}

__global__ __launch_bounds__(256) void
fp32_to_fp64_pulse_kernel(const fvec4* __restrict__ in,
                          fvec4* __restrict__ out) {
    int lane = threadIdx.x & 63;
    int w = (int)((blockIdx.x * blockDim.x + threadIdx.x) >> 6);

    int sh   = lane & 56;        // 8 * (lane/8): ballot byte for my row
    int src0 = (lane & 48) >> 1; // 8 * (lane/16): holder of row lane/16
    int nsh  = (lane & 15) * 4;  // my nibble within the redistributed row

    // ---- 2 tiles per wave, both loads in flight before first ballot ----
    const fvec4* ib = in + (size_t)w * 128 + lane;
    fvec4 g0 = __builtin_nontemporal_load(ib);
    fvec4 g1 = __builtin_nontemporal_load(ib + 64);

    fvec4* ob = out + (size_t)w * 256 + lane;
    process_tile(g0, sh, src0, nsh, ob);
    process_tile(g1, sh, src0, nsh, ob + 128);
}

extern "C" void kernel_launch(void* const* d_in, const int* in_sizes, int n_in,
                              void* d_out, int out_size, void* d_ws, size_t ws_size,
                              hipStream_t stream) {
    (void)n_in; (void)d_ws; (void)ws_size; (void)out_size;
    const fvec4* in = (const fvec4*)d_in[0];
    fvec4* out = (fvec4*)d_out;
    int nrows  = in_sizes[0] / 32;       // B = 2097152
    int nwaves = nrows / 16;             // 16 rows (2 tiles) per wave
    int threads = nwaves * 64;
    const int block = 256;
    int grid = threads / block;          // exact: B divisible by 64
    fp32_to_fp64_pulse_kernel<<<grid, block, 0, stream>>>(in, out);
}

// Round 9
// 658.576 us; speedup vs baseline: 1.0155x; 1.0155x over previous
//
#include <hip/hip_runtime.h>
#include <stdint.h>

// FP32->FP64 bit-pulse converter — FINAL (round 7 structure, best: 657 us).
//
// Wave tile = 8 rows (1024 B in / 2048 B out), 1 tile per wave.
//  Load:  lane k loads float4 #k (fully coalesced 1024 B/instr, nontemporal).
//  Pack:  4 ballots -> all 256 tile bits in wave-uniform 64-bit masks.
//  Convert: lane k rebuilds row lane/8's 32-bit MSB-first word via
//           nibble-spread of the ballot bytes, then does the integer
//           FP32->FP64 bit conversion (rebias +896, mant<<29, NaN/Inf fix).
//  Shuffle: two 64-bit ds_bpermute redistributions so each store
//           instruction writes a CONTIGUOUS aligned 1024-B span
//           (full sector coverage; -12 us vs stride-2 stores).
//  Store: nontemporal (write-once 512-MiB stream; -5 us).
//
// Measured ladder: naive/row 772 -> ballot+stride2 674 -> contiguous
// stores 662 -> nt stores 657. Per-wave load batching (2 and 4 tiles)
// regressed 3x — TLP at 8 waves/SIMD already saturates the memory queues.
// Kernel portion ~145 us vs 122 us pure-stream floor on 768 MiB; residual
// is mixed read/write bus turnaround (fills hit 6.3 TB/s pure-write in the
// same captures). This is the mixed-stream HBM roofline.

typedef float fvec4 __attribute__((ext_vector_type(4)));

__device__ __forceinline__ uint32_t spread4(uint32_t x) {
    // spread low 8 bits: bit i -> bit 4*i
    x &= 0xffu;
    x = (x | (x << 12)) & 0x000F000Fu;
    x = (x | (x << 6))  & 0x03030303u;
    x = (x | (x << 3))  & 0x11111111u;
    return x;
}

__device__ __forceinline__ uint64_t shfl64(uint64_t x, int srcLane) {
    int addr = srcLane << 2;  // ds_bpermute index is lane*4 bytes
    uint32_t lo = (uint32_t)__builtin_amdgcn_ds_bpermute(addr, (int)(uint32_t)x);
    uint32_t hi = (uint32_t)__builtin_amdgcn_ds_bpermute(addr, (int)(uint32_t)(x >> 32));
    return ((uint64_t)hi << 32) | lo;
}

__device__ __forceinline__ fvec4 nib2f(uint32_t nib) {
    fvec4 f;
    f.x = (nib & 1u) ? 1.0f : 0.0f;
    f.y = (nib & 2u) ? 1.0f : 0.0f;
    f.z = (nib & 4u) ? 1.0f : 0.0f;
    f.w = (nib & 8u) ? 1.0f : 0.0f;
    return f;
}

__global__ __launch_bounds__(256) void
fp32_to_fp64_pulse_kernel(const fvec4* __restrict__ in,
                          fvec4* __restrict__ out) {
    int lane = threadIdx.x & 63;
    int w = (int)((blockIdx.x * blockDim.x + threadIdx.x) >> 6);

    // ---- coalesced load: 8 rows = 64 float4 (nontemporal, read-once) ----
    fvec4 g = __builtin_nontemporal_load(in + (size_t)w * 64 + lane);

    // ---- pack all 256 tile bits: bit k of bc = (elem 4k+c of tile) != 0 ----
    uint64_t b0 = __ballot(g.x != 0.0f);
    uint64_t b1 = __ballot(g.y != 0.0f);
    uint64_t b2 = __ballot(g.z != 0.0f);
    uint64_t b3 = __ballot(g.w != 0.0f);

    // ---- rebuild this lane's row word (row = lane/8, MSB-first) ----
    int sh = lane & 56;  // 8 * (lane/8)
    uint32_t u = spread4((uint32_t)(b0 >> sh))
               | (spread4((uint32_t)(b1 >> sh)) << 1)
               | (spread4((uint32_t)(b2 >> sh)) << 2)
               | (spread4((uint32_t)(b3 >> sh)) << 3);

    // ---- FP32 -> FP64 bit conversion (once per lane) ----
    uint32_t v = __brev(u);              // standard IEEE FP32 word
    uint32_t E = (v >> 23) & 0xffu;
    uint32_t M = v & 0x7fffffu;
    uint64_t S = (uint64_t)(v >> 31);
    uint64_t E64 = E ? (uint64_t)(E + 896u) : 0ull;  // rebias 1023-127
    uint64_t M64 = (uint64_t)M << 29;
    if (E == 255u) {                     // Inf / NaN
        E64 = 2047ull;
        M64 = M ? (1ull << 51) : 0ull;   // quiet NaN: mantissa MSB only
    }
    uint64_t v64 = (S << 63) | (E64 << 52) | M64;
    uint64_t rr  = __brevll(v64);        // bit j == output element j of row

    // ---- redistribute rows so each store is a contiguous 1024-B span ----
    int src0 = (lane & 48) >> 1;         // 8 * (lane/16): holder of row lane/16
    uint64_t r0 = shfl64(rr, src0);      // row lane/16      (chunks 0..63)
    uint64_t r1 = shfl64(rr, src0 + 32); // row 4 + lane/16  (chunks 64..127)

    int nsh = (lane & 15) * 4;           // my nibble within the row
    fvec4 f0 = nib2f((uint32_t)(r0 >> nsh) & 0xfu);
    fvec4 f1 = nib2f((uint32_t)(r1 >> nsh) & 0xfu);

    fvec4* ob = out + (size_t)w * 128 + lane;
    __builtin_nontemporal_store(f0, ob);       // chunks 0..63
    __builtin_nontemporal_store(f1, ob + 64);  // chunks 64..127
}

extern "C" void kernel_launch(void* const* d_in, const int* in_sizes, int n_in,
                              void* d_out, int out_size, void* d_ws, size_t ws_size,
                              hipStream_t stream) {
    (void)n_in; (void)d_ws; (void)ws_size; (void)out_size;
    const fvec4* in = (const fvec4*)d_in[0];
    fvec4* out = (fvec4*)d_out;
    int nrows  = in_sizes[0] / 32;       // B = 2097152
    int nwaves = nrows / 8;              // 8 rows per wave
    int threads = nwaves * 64;
    const int block = 256;
    int grid = threads / block;          // exact: B divisible by 32
    fp32_to_fp64_pulse_kernel<<<grid, block, 0, stream>>>(in, out);
}